// Round 3
// baseline (1959.398 us; speedup 1.0000x reference)
//
#include <hip/hip_runtime.h>

#define BT   4      // batch tile per block
#define HID  64
#define G4   256    // 4*HID
#define SEQ  512
#define NOUT 12

typedef float f2 __attribute__((ext_vector_type(2)));

__device__ __forceinline__ float sigf(float x)  { return 1.f / (1.f + __expf(-x)); }
__device__ __forceinline__ float tanhf_fast(float x) { return 1.f - 2.f / (1.f + __expf(2.f * x)); }

// Load 64 weights (row g of a [256,64] matrix) into 32 f2 SSA values (even-aligned pairs).
#define LOAD_ROW_F2(M, W)                                                  \
    {                                                                      \
        const float4* p = (const float4*)&M[g * HID];                      \
        _Pragma("unroll")                                                  \
        for (int j = 0; j < 16; ++j) {                                     \
            float4 q = p[j];                                               \
            W[2 * j + 0] = f2{q.x, q.y};                                   \
            W[2 * j + 1] = f2{q.z, q.w};                                   \
        }                                                                  \
    }

// Two-layer software pipeline (gates0(t+1) + gates1(t) in one gemm phase),
// all dot arithmetic as packed-f32 FMA (v_pk_fma_f32): 384 pk-FMA/thread/step.
__global__ void __launch_bounds__(256) __attribute__((amdgpu_waves_per_eu(2, 2)))
lstm2_fused(
    const float* __restrict__ x,      // [B, SEQ, 1]
    const float* __restrict__ w_ih0,  // [256, 1]
    const float* __restrict__ w_hh0,  // [256, 64]
    const float* __restrict__ b_ih0,  // [256]
    const float* __restrict__ b_hh0,  // [256]
    const float* __restrict__ w_ih1,  // [256, 64]
    const float* __restrict__ w_hh1,  // [256, 64]
    const float* __restrict__ b_ih1,  // [256]
    const float* __restrict__ b_hh1,  // [256]
    const float* __restrict__ fc_w,   // [12, 64]
    const float* __restrict__ fc_b,   // [12]
    float* __restrict__ out)          // [B, 12]
{
    __shared__ float xs[BT][SEQ];    // 8 KB
    __shared__ float h0s[BT][HID];   // 1 KB
    __shared__ float h1s[BT][HID];   // 1 KB
    __shared__ float gs0[BT][G4];    // 4 KB  gates layer0, step t+1
    __shared__ float gs1[BT][G4];    // 4 KB  gates layer1, step t

    const int tid = threadIdx.x;
    const int g   = tid;              // gate row owned by this thread
    const int b0  = blockIdx.x * BT;

    // ---- loop-invariant weights as f2 pairs (96 f2 = 192 regs, VGPR+AGPR) ----
    f2 w0p[32], wip[32], w1p[32];
    LOAD_ROW_F2(w_hh0, w0p);
    LOAD_ROW_F2(w_ih1, wip);
    LOAD_ROW_F2(w_hh1, w1p);

    const float wih0g = w_ih0[g];                    // input size == 1
    const float bias0 = b_ih0[g] + b_hh0[g];
    const float bias1 = b_ih1[g] + b_hh1[g];

    // ---- stage this block's x tile into LDS ----
    for (int i = tid; i < BT * SEQ; i += 256) {
        int b = i >> 9, t = i & (SEQ - 1);
        xs[b][t] = x[(size_t)(b0 + b) * SEQ + t];
    }
    for (int i = tid; i < BT * HID; i += 256) {
        ((float*)h0s)[i] = 0.f;
        ((float*)h1s)[i] = 0.f;
    }
    const int eb = tid >> 6;     // batch in tile (elementwise phase)
    const int ej = tid & 63;     // hidden unit   (elementwise phase)
    float c0 = 0.f, c1 = 0.f;
    __syncthreads();

    // ===== prologue: gates0(0) = bias0 + x[0]*w_ih0  (h0 init = 0) =====
#pragma unroll
    for (int b = 0; b < BT; ++b) gs0[b][g] = fmaf(xs[b][0], wih0g, bias0);
    __syncthreads();
    {   // ew0 -> h0(0), c0(0)
        float ig = sigf(gs0[eb][ej]);
        float fg = sigf(gs0[eb][64 + ej]);
        float gg = tanhf_fast(gs0[eb][128 + ej]);
        float og = sigf(gs0[eb][192 + ej]);
        c0 = fg * c0 + ig * gg;
        h0s[eb][ej] = og * tanhf_fast(c0);
    }
    __syncthreads();

    for (int t = 0; t < SEQ; ++t) {
        const int tx = (t + 1 < SEQ) ? (t + 1) : (SEQ - 1);  // clamped dummy at t=511
        f2 a0p[BT], a1p[BT];
        // a0p[b] -> gates0(t+1)[g] = bias0 + x[t+1]*w_ih0[g] + h0(t) . w_hh0[g]
        // a1p[b] -> gates1(t)[g]   = bias1 + h0(t) . w_ih1[g] + h1(t-1) . w_hh1[g]
#pragma unroll
        for (int b = 0; b < BT; ++b) {
            a0p[b] = f2{fmaf(xs[b][tx], wih0g, bias0), 0.f};
            a1p[b] = f2{bias1, 0.f};
        }
#pragma unroll
        for (int k = 0; k < 32; k += 2) {        // 4 h-floats (= one b128) per batch per layer
#pragma unroll
            for (int b = 0; b < BT; ++b) {
                float4 h0v = *(const float4*)&h0s[b][2 * k];   // broadcast, feeds 8 pk-FMAs
                float4 h1v = *(const float4*)&h1s[b][2 * k];   // broadcast, feeds 4 pk-FMAs
                f2 h0a = f2{h0v.x, h0v.y}, h0b = f2{h0v.z, h0v.w};
                f2 h1a = f2{h1v.x, h1v.y}, h1b = f2{h1v.z, h1v.w};
                a0p[b] = __builtin_elementwise_fma(h0a, w0p[k + 0], a0p[b]);
                a0p[b] = __builtin_elementwise_fma(h0b, w0p[k + 1], a0p[b]);
                a1p[b] = __builtin_elementwise_fma(h0a, wip[k + 0], a1p[b]);
                a1p[b] = __builtin_elementwise_fma(h0b, wip[k + 1], a1p[b]);
                a1p[b] = __builtin_elementwise_fma(h1a, w1p[k + 0], a1p[b]);
                a1p[b] = __builtin_elementwise_fma(h1b, w1p[k + 1], a1p[b]);
            }
        }
#pragma unroll
        for (int b = 0; b < BT; ++b) {
            gs0[b][g] = a0p[b][0] + a0p[b][1];
            gs1[b][g] = a1p[b][0] + a1p[b][1];
        }
        __syncthreads();

        // ===== merged elementwise phase: ew0(t+1) and ew1(t) =====
        {
            float ig = sigf(gs0[eb][ej]);
            float fg = sigf(gs0[eb][64 + ej]);
            float gg = tanhf_fast(gs0[eb][128 + ej]);
            float og = sigf(gs0[eb][192 + ej]);
            c0 = fg * c0 + ig * gg;
            h0s[eb][ej] = og * tanhf_fast(c0);

            float ig1 = sigf(gs1[eb][ej]);
            float fg1 = sigf(gs1[eb][64 + ej]);
            float gg1 = tanhf_fast(gs1[eb][128 + ej]);
            float og1 = sigf(gs1[eb][192 + ej]);
            c1 = fg1 * c1 + ig1 * gg1;
            h1s[eb][ej] = og1 * tanhf_fast(c1);
        }
        __syncthreads();
    }

    // ===== final projection: out[b][o] = fc_b[o] + h1(511) . fc_w[o] =====
    if (tid < BT * NOUT) {
        int b = tid / NOUT, o = tid % NOUT;
        float acc = fc_b[o];
#pragma unroll
        for (int j = 0; j < HID; ++j)
            acc = fmaf(fc_w[o * HID + j], h1s[b][j], acc);
        out[(size_t)(b0 + b) * NOUT + o] = acc;
    }
}

extern "C" void kernel_launch(void* const* d_in, const int* in_sizes, int n_in,
                              void* d_out, int out_size, void* d_ws, size_t ws_size,
                              hipStream_t stream) {
    const float* x     = (const float*)d_in[0];
    const float* w_ih0 = (const float*)d_in[1];
    const float* w_hh0 = (const float*)d_in[2];
    const float* b_ih0 = (const float*)d_in[3];
    const float* b_hh0 = (const float*)d_in[4];
    const float* w_ih1 = (const float*)d_in[5];
    const float* w_hh1 = (const float*)d_in[6];
    const float* b_ih1 = (const float*)d_in[7];
    const float* b_hh1 = (const float*)d_in[8];
    const float* fc_w  = (const float*)d_in[9];
    const float* fc_b  = (const float*)d_in[10];

    const int B = in_sizes[0] / SEQ;          // 2048
    dim3 grid(B / BT);                        // 512 blocks -> 2 blocks/CU
    lstm2_fused<<<grid, 256, 0, stream>>>(x, w_ih0, w_hh0, b_ih0, b_hh0,
                                          w_ih1, w_hh1, b_ih1, b_hh1,
                                          fc_w, fc_b, (float*)d_out);
}